// Round 1
// baseline (73.047 us; speedup 1.0000x reference)
//
#include <hip/hip_runtime.h>

#define SDIM 1024

typedef __attribute__((ext_vector_type(8))) short bf16x8;
typedef __attribute__((ext_vector_type(4))) float f32x4;

union FragU { unsigned int u[4]; bf16x8 f; };

__device__ __forceinline__ float fast_gelu(float t) {
    // jax.nn.gelu approximate=True: 0.5*t*(1+tanh(sqrt(2/pi)*(t+0.044715 t^3)))
    //                             = t * sigmoid(2*sqrt(2/pi)*(t+0.044715 t^3))
    float t2 = t * t;
    float pl = __builtin_fmaf(t2, 0.044715f, 1.0f);
    float zneg = (-1.5957691216057308f * t) * pl;   // -2*sqrt(2/pi)*t*(1+0.044715 t^2)
    float e = __expf(zneg);
    float den = 1.0f + e;
    return t * __builtin_amdgcn_rcpf(den);
}

__device__ __forceinline__ unsigned int pack2_bf16(float g0, float g1) {
    // round-to-nearest (half away) bf16 pack: low short = g0, high short = g1
    unsigned int b0 = __float_as_uint(g0) + 0x8000u;
    unsigned int b1 = __float_as_uint(g1) + 0x8000u;
    return (b0 >> 16) | (b1 & 0xFFFF0000u);
}

// ---------------- Kernel 1: u[b,s,64] = xc@W1[:32] + b1 ; v = xc@W1[32:] ----------------
// xc = x@Wc + bc. One block handles 8 (b,s) rows. Grid = B*S/8 = 256.
__global__ __launch_bounds__(256) void compute_uv(
    const float* __restrict__ x, const float* __restrict__ Wc,
    const float* __restrict__ bc, const float* __restrict__ W1,
    const float* __restrict__ b1, float* __restrict__ u, float* __restrict__ v)
{
    __shared__ float xrow[8 * 1024];
    __shared__ float part[8 * 8 * 32];
    __shared__ float xc[8 * 32];
    const int tid = threadIdx.x;
    const size_t bs0 = (size_t)blockIdx.x * 8;   // first flat row index (b*S+s)

    const float4* xin = (const float4*)(x + bs0 * 1024);
    #pragma unroll
    for (int rr = 0; rr < 8; ++rr)
        ((float4*)xrow)[rr * 256 + tid] = xin[rr * 256 + tid];
    __syncthreads();

    {
        const int c = tid & 31, p = tid >> 5;
        float acc[8] = {0.f,0.f,0.f,0.f,0.f,0.f,0.f,0.f};
        for (int d = p * 128; d < p * 128 + 128; ++d) {
            const float wv = Wc[d * 32 + c];
            #pragma unroll
            for (int r = 0; r < 8; ++r)
                acc[r] = __builtin_fmaf(xrow[r * 1024 + d], wv, acc[r]);
        }
        #pragma unroll
        for (int r = 0; r < 8; ++r)
            part[r * 256 + p * 32 + c] = acc[r];
    }
    __syncthreads();
    {
        const int r = tid >> 5, c = tid & 31;
        float s = bc[c];
        #pragma unroll
        for (int p = 0; p < 8; ++p) s += part[r * 256 + p * 32 + c];
        xc[r * 32 + c] = s;
    }
    __syncthreads();
    {
        const int h = tid & 63;
        const int rq = tid >> 6;
        #pragma unroll
        for (int q = 0; q < 2; ++q) {
            const int rr = rq + q * 4;
            float ua = b1[h], va = 0.0f;
            #pragma unroll
            for (int cc = 0; cc < 32; ++cc) {
                const float xv = xc[rr * 32 + cc];
                ua = __builtin_fmaf(xv, W1[cc * 64 + h], ua);
                va = __builtin_fmaf(xv, W1[(32 + cc) * 64 + h], va);
            }
            u[(bs0 + rr) * 64 + h] = ua;
            v[(bs0 + rr) * 64 + h] = va;
        }
    }
}

// ---------------- Kernel 2: out[b,h,i,j] = sum_k gelu(u[i,k]+v[j,k]) * W2[k,h] + b2[h] --
// D = W2^T (16h x 64k) @ G^T (64k x 16j) via 2x mfma_f32_16x16x32_bf16.
// Block: 256 thr = 4 waves; tile = 16 i x 64 j (wave w owns j-group w). Grid (16,64,2).
__global__ __launch_bounds__(256) void prg_main(
    const float* __restrict__ u, const float* __restrict__ v,
    const float* __restrict__ W2, const float* __restrict__ b2,
    float* __restrict__ out)
{
    const int tid  = threadIdx.x;
    const int lane = tid & 63;
    const int w    = tid >> 6;
    const int jb   = blockIdx.x * 64;
    const int ib   = blockIdx.y * 16;
    const int b    = blockIdx.z;

    __shared__ float u_lds[16][64];

    // stage u tile (16 rows x 64 k, 4KB)
    {
        const int row = tid >> 4;
        const int col = (tid & 15) * 4;
        *(float4*)&u_lds[row][col] =
            *(const float4*)(u + ((size_t)(b * SDIM + ib + row) * 64 + col));
    }

    const int lg = lane >> 4;   // k-group 0..3
    const int lr = lane & 15;   // fragment row/col
    const int k0 = lg * 8;

    // v fragment source, kept in registers: j = jb + w*16 + lr
    const int j = jb + w * 16 + lr;
    const float* vp = v + ((size_t)(b * SDIM + j) * 64);
    const float4 v0 = *(const float4*)(vp + k0);
    const float4 v1 = *(const float4*)(vp + k0 + 4);
    const float4 v2 = *(const float4*)(vp + k0 + 32);
    const float4 v3 = *(const float4*)(vp + k0 + 36);

    // A operand = W2^T: row h = lr, k = k0+e (lo) / k0+32+e (hi)
    FragU w2lo, w2hi;
    #pragma unroll
    for (int e = 0; e < 4; ++e) {
        w2lo.u[e] = pack2_bf16(W2[(k0 + 2*e) * 16 + lr],      W2[(k0 + 2*e + 1) * 16 + lr]);
        w2hi.u[e] = pack2_bf16(W2[(k0 + 32 + 2*e) * 16 + lr], W2[(k0 + 32 + 2*e + 1) * 16 + lr]);
    }

    // accumulator init: D row = h = lg*4 + r (m89-verified C/D layout)
    const float b2r0 = b2[lg * 4 + 0];
    const float b2r1 = b2[lg * 4 + 1];
    const float b2r2 = b2[lg * 4 + 2];
    const float b2r3 = b2[lg * 4 + 3];

    __syncthreads();

    // out[((b*16+h)*S + i)*S + j], h = lg*4 + r, col (lane&15) = j  -> 64B coalesced per h-row
    float* ob = out + ((size_t)(b * 16 + lg * 4) * SDIM + ib) * SDIM + j;

    #pragma unroll
    for (int il = 0; il < 16; ++il) {
        const float4 a0 = *(const float4*)&u_lds[il][k0];
        const float4 a1 = *(const float4*)&u_lds[il][k0 + 4];
        FragU glo;
        glo.u[0] = pack2_bf16(fast_gelu(a0.x + v0.x), fast_gelu(a0.y + v0.y));
        glo.u[1] = pack2_bf16(fast_gelu(a0.z + v0.z), fast_gelu(a0.w + v0.w));
        glo.u[2] = pack2_bf16(fast_gelu(a1.x + v1.x), fast_gelu(a1.y + v1.y));
        glo.u[3] = pack2_bf16(fast_gelu(a1.z + v1.z), fast_gelu(a1.w + v1.w));
        const float4 a2 = *(const float4*)&u_lds[il][k0 + 32];
        const float4 a3 = *(const float4*)&u_lds[il][k0 + 36];
        FragU ghi;
        ghi.u[0] = pack2_bf16(fast_gelu(a2.x + v2.x), fast_gelu(a2.y + v2.y));
        ghi.u[1] = pack2_bf16(fast_gelu(a2.z + v2.z), fast_gelu(a2.w + v2.w));
        ghi.u[2] = pack2_bf16(fast_gelu(a3.x + v3.x), fast_gelu(a3.y + v3.y));
        ghi.u[3] = pack2_bf16(fast_gelu(a3.z + v3.z), fast_gelu(a3.w + v3.w));

        f32x4 acc = {b2r0, b2r1, b2r2, b2r3};
        acc = __builtin_amdgcn_mfma_f32_16x16x32_bf16(w2lo.f, glo.f, acc, 0, 0, 0);
        acc = __builtin_amdgcn_mfma_f32_16x16x32_bf16(w2hi.f, ghi.f, acc, 0, 0, 0);

        float* o = ob + (size_t)il * SDIM;
        o[0]                              = acc[0];
        o[(size_t)1 * SDIM * SDIM]        = acc[1];
        o[(size_t)2 * SDIM * SDIM]        = acc[2];
        o[(size_t)3 * SDIM * SDIM]        = acc[3];
    }
}

extern "C" void kernel_launch(void* const* d_in, const int* in_sizes, int n_in,
                              void* d_out, int out_size, void* d_ws, size_t ws_size,
                              hipStream_t stream) {
    const float* x  = (const float*)d_in[0];
    const float* Wc = (const float*)d_in[1];
    const float* bc = (const float*)d_in[2];
    const float* W1 = (const float*)d_in[3];
    const float* b1 = (const float*)d_in[4];
    const float* W2 = (const float*)d_in[5];
    const float* b2 = (const float*)d_in[6];
    float* out = (float*)d_out;

    float* u = (float*)d_ws;                 // [B*S*64] fp32 = 512 KB
    float* v = u + 2 * SDIM * 64;            // [B*S*64] fp32 = 512 KB

    compute_uv<<<dim3(256), dim3(256), 0, stream>>>(x, Wc, bc, W1, b1, u, v);
    prg_main<<<dim3(16, 64, 2), dim3(256), 0, stream>>>(u, v, W2, b2, out);
}

// Round 3
// 57.532 us; speedup vs baseline: 1.2697x; 1.2697x over previous
//
#include <hip/hip_runtime.h>
#include <hip/hip_fp16.h>

#define SDIM 1024

typedef _Float16 f16;
typedef _Float16 f16x8 __attribute__((ext_vector_type(8)));
typedef __attribute__((ext_vector_type(4))) float f32x4;

union FragH { unsigned int u[4]; f16x8 f; };

// packed-f16 tanh-gelu on 2 elements: g = t * sigmoid(2*sqrt(2/pi)*(t+0.044715 t^3))
// exp2 form: z2 = c2*t*(1+0.044715 t^2), c2 = -2*sqrt(2/pi)*log2(e) = -2.3022082
// then sig = 1/(1+2^z2). f16-saturation safe: t<<0 -> 2^z2=inf -> rcp=0 -> g=0.
__device__ __forceinline__ unsigned int addgelu_pair(unsigned int au, unsigned int bu) {
    const __half2 k044 = __float2half2_rn(0.044715f);
    const __half2 one  = __float2half2_rn(1.0f);
    const __half2 cz   = __float2half2_rn(-2.3022082f);
    union { unsigned int u; __half2 h; } A, B, G;
    A.u = au; B.u = bu;
    __half2 t  = __hadd2(A.h, B.h);
    __half2 t2 = __hmul2(t, t);
    __half2 pl = __hfma2(t2, k044, one);
    __half2 z  = __hmul2(__hmul2(t, cz), pl);
    __half2 e  = h2exp2(z);
    __half2 r  = h2rcp(__hadd2(e, one));
    G.h = __hmul2(t, r);
    return G.u;
}

// ---------------- Kernel 1: u[b,s,64] = xc@W1[:32] + b1 ; v = xc@W1[32:] (f16 out) -----
__global__ __launch_bounds__(256) void compute_uv(
    const float* __restrict__ x, const float* __restrict__ Wc,
    const float* __restrict__ bc, const float* __restrict__ W1,
    const float* __restrict__ b1, f16* __restrict__ u, f16* __restrict__ v)
{
    __shared__ float xrow[8 * 1024];
    __shared__ float part[8 * 8 * 32];
    __shared__ float xc[8 * 32];
    const int tid = threadIdx.x;
    const size_t bs0 = (size_t)blockIdx.x * 8;

    const float4* xin = (const float4*)(x + bs0 * 1024);
    #pragma unroll
    for (int rr = 0; rr < 8; ++rr)
        ((float4*)xrow)[rr * 256 + tid] = xin[rr * 256 + tid];
    __syncthreads();

    {
        const int c = tid & 31, p = tid >> 5;
        float acc[8] = {0.f,0.f,0.f,0.f,0.f,0.f,0.f,0.f};
        for (int d = p * 128; d < p * 128 + 128; ++d) {
            const float wv = Wc[d * 32 + c];
            #pragma unroll
            for (int r = 0; r < 8; ++r)
                acc[r] = __builtin_fmaf(xrow[r * 1024 + d], wv, acc[r]);
        }
        #pragma unroll
        for (int r = 0; r < 8; ++r)
            part[r * 256 + p * 32 + c] = acc[r];
    }
    __syncthreads();
    {
        const int r = tid >> 5, c = tid & 31;
        float s = bc[c];
        #pragma unroll
        for (int p = 0; p < 8; ++p) s += part[r * 256 + p * 32 + c];
        xc[r * 32 + c] = s;
    }
    __syncthreads();
    {
        const int h = tid & 63;
        const int rq = tid >> 6;
        #pragma unroll
        for (int q = 0; q < 2; ++q) {
            const int rr = rq + q * 4;
            float ua = b1[h], va = 0.0f;
            #pragma unroll
            for (int cc = 0; cc < 32; ++cc) {
                const float xv = xc[rr * 32 + cc];
                ua = __builtin_fmaf(xv, W1[cc * 64 + h], ua);
                va = __builtin_fmaf(xv, W1[(32 + cc) * 64 + h], va);
            }
            u[(bs0 + rr) * 64 + h] = (f16)ua;
            v[(bs0 + rr) * 64 + h] = (f16)va;
        }
    }
}

// ---------------- Kernel 2: out[b,h,i,j] = sum_k gelu(u[i,k]+v[j,k]) * W2[k,h] + b2[h] --
// D = W2^T (16h x 64k) @ G^T (64k x 16j) via 2x mfma_f32_16x16x32_f16.
__global__ __launch_bounds__(256) void prg_main(
    const f16* __restrict__ u, const f16* __restrict__ v,
    const float* __restrict__ W2, const float* __restrict__ b2,
    float* __restrict__ out)
{
    const int tid  = threadIdx.x;
    const int lane = tid & 63;
    const int w    = tid >> 6;
    const int jb   = blockIdx.x * 64;
    const int ib   = blockIdx.y * 16;
    const int b    = blockIdx.z;

    __shared__ f16 u_lds[16][64];   // 2 KB

    if (tid < 128) {
        const int row = tid >> 3;
        const int col = (tid & 7) * 8;
        *(uint4*)&u_lds[row][col] =
            *(const uint4*)(u + ((size_t)(b * SDIM + ib + row) * 64 + col));
    }

    const int lg = lane >> 4;   // k-group 0..3
    const int lr = lane & 15;   // fragment row (h for A) / col (j for B/D)
    const int k0 = lg * 8;

    const int j = jb + w * 16 + lr;
    const f16* vp = v + ((size_t)(b * SDIM + j) * 64);
    const uint4 vlo = *(const uint4*)(vp + k0);        // k0..k0+7
    const uint4 vhi = *(const uint4*)(vp + k0 + 32);   // k0+32..k0+39

    // A operand = W2^T (f16): row h = lr, k pairs (k0+2e, k0+2e+1)
    FragH w2lo, w2hi;
    #pragma unroll
    for (int e = 0; e < 4; ++e) {
        union { unsigned int u; __half2 h; } a, c;
        a.h = __floats2half2_rn(W2[(k0 + 2*e) * 16 + lr],      W2[(k0 + 2*e + 1) * 16 + lr]);
        c.h = __floats2half2_rn(W2[(k0 + 32 + 2*e) * 16 + lr], W2[(k0 + 32 + 2*e + 1) * 16 + lr]);
        w2lo.u[e] = a.u;
        w2hi.u[e] = c.u;
    }

    const float b2r0 = b2[lg * 4 + 0];
    const float b2r1 = b2[lg * 4 + 1];
    const float b2r2 = b2[lg * 4 + 2];
    const float b2r3 = b2[lg * 4 + 3];

    __syncthreads();

    // D layout: col (lane&15) = j, row h = lg*4 + r  -> 64B-coalesced per h-plane
    float* ob = out + ((size_t)(b * 16 + lg * 4) * SDIM + ib) * SDIM + j;

    #pragma unroll 4
    for (int il = 0; il < 16; ++il) {
        const uint4 alo = *(const uint4*)&u_lds[il][k0];
        const uint4 ahi = *(const uint4*)&u_lds[il][k0 + 32];

        FragH glo, ghi;
        glo.u[0] = addgelu_pair(alo.x, vlo.x);
        glo.u[1] = addgelu_pair(alo.y, vlo.y);
        glo.u[2] = addgelu_pair(alo.z, vlo.z);
        glo.u[3] = addgelu_pair(alo.w, vlo.w);
        ghi.u[0] = addgelu_pair(ahi.x, vhi.x);
        ghi.u[1] = addgelu_pair(ahi.y, vhi.y);
        ghi.u[2] = addgelu_pair(ahi.z, vhi.z);
        ghi.u[3] = addgelu_pair(ahi.w, vhi.w);

        f32x4 acc = {b2r0, b2r1, b2r2, b2r3};
        acc = __builtin_amdgcn_mfma_f32_16x16x32_f16(w2lo.f, glo.f, acc, 0, 0, 0);
        acc = __builtin_amdgcn_mfma_f32_16x16x32_f16(w2hi.f, ghi.f, acc, 0, 0, 0);

        float* o = ob + (size_t)il * SDIM;
        o[0]                       = acc[0];
        o[(size_t)1 * SDIM * SDIM] = acc[1];
        o[(size_t)2 * SDIM * SDIM] = acc[2];
        o[(size_t)3 * SDIM * SDIM] = acc[3];
    }
}

extern "C" void kernel_launch(void* const* d_in, const int* in_sizes, int n_in,
                              void* d_out, int out_size, void* d_ws, size_t ws_size,
                              hipStream_t stream) {
    const float* x  = (const float*)d_in[0];
    const float* Wc = (const float*)d_in[1];
    const float* bc = (const float*)d_in[2];
    const float* W1 = (const float*)d_in[3];
    const float* b1 = (const float*)d_in[4];
    const float* W2 = (const float*)d_in[5];
    const float* b2 = (const float*)d_in[6];
    float* out = (float*)d_out;

    f16* u = (f16*)d_ws;                 // [B*S*64] f16 = 256 KB
    f16* v = u + 2 * SDIM * 64;          // [B*S*64] f16 = 256 KB

    compute_uv<<<dim3(256), dim3(256), 0, stream>>>(x, Wc, bc, W1, b1, u, v);
    prg_main<<<dim3(16, 64, 2), dim3(256), 0, stream>>>(u, v, W2, b2, out);
}

// Round 5
// 56.624 us; speedup vs baseline: 1.2900x; 1.0160x over previous
//
#include <hip/hip_runtime.h>
#include <hip/hip_fp16.h>

#define SDIM 1024

typedef _Float16 f16;
typedef _Float16 f16x8 __attribute__((ext_vector_type(8)));
typedef __attribute__((ext_vector_type(4))) float f32x4;

union FragH { unsigned int u[4]; f16x8 f; };
union H2U  { unsigned int u; __half2 h; };

// packed-f16 tanh-gelu on 2 elements: g = t * sigmoid(2*sqrt(2/pi)*(t+0.044715 t^3))
// exp2 form: z = c2*t*(1+0.044715 t^2), c2 = -2*sqrt(2/pi)*log2(e); sig = 1/(1+2^z).
// Saturation-safe: t<<0 -> 2^z=inf -> rcp=0 -> g=0; t>>0 -> 2^z=0 -> g=t.
// Trans path: scalar VOP1 per half (op_sel is NOT supported on gfx950 trans ops),
// repacked with one v_pack_b32_f16. 13 instrs/pair, 4 trans, no OCML.
__device__ __forceinline__ unsigned int addgelu_pair(unsigned int au, unsigned int bu) {
    const __half2 k044 = __float2half2_rn(0.044715f);
    const __half2 one  = __float2half2_rn(1.0f);
    const __half2 cz   = __float2half2_rn(-2.3022082f);
    H2U A, B, Z, R, G;
    A.u = au; B.u = bu;
    __half2 t  = __hadd2(A.h, B.h);          // v_pk_add_f16
    __half2 t2 = __hmul2(t, t);              // v_pk_mul_f16
    __half2 pl = __hfma2(t2, k044, one);     // v_pk_fma_f16
    Z.h = __hmul2(__hmul2(t, cz), pl);       // 2x v_pk_mul_f16
    unsigned int zh = Z.u >> 16;             // v_lshrrev_b32
    unsigned int el, eh, dl, dh, rl, rh, ru;
    asm("v_exp_f16 %0, %1"      : "=v"(el) : "v"(Z.u));
    asm("v_exp_f16 %0, %1"      : "=v"(eh) : "v"(zh));
    asm("v_add_f16 %0, %1, 1.0" : "=v"(dl) : "v"(el));
    asm("v_add_f16 %0, %1, 1.0" : "=v"(dh) : "v"(eh));
    asm("v_rcp_f16 %0, %1"      : "=v"(rl) : "v"(dl));
    asm("v_rcp_f16 %0, %1"      : "=v"(rh) : "v"(dh));
    asm("v_pack_b32_f16 %0, %1, %2" : "=v"(ru) : "v"(rl), "v"(rh));
    R.u = ru;
    G.h = __hmul2(t, R.h);                   // v_pk_mul_f16
    return G.u;
}

// ---------------- Kernel 1: u[b,s,64] = xc@W1[:32] + b1 ; v = xc@W1[32:] (f16 out) -----
// xc = x@Wc + bc. 4 rows per block, grid = B*S/4 = 512 (2 blocks/CU).
__global__ __launch_bounds__(256) void compute_uv(
    const float* __restrict__ x, const float* __restrict__ Wc,
    const float* __restrict__ bc, const float* __restrict__ W1,
    const float* __restrict__ b1, f16* __restrict__ u, f16* __restrict__ v)
{
    __shared__ float xrow[4 * 1024];
    __shared__ float part[4 * 8 * 32];
    __shared__ float xc[4 * 32];
    const int tid = threadIdx.x;
    const size_t bs0 = (size_t)blockIdx.x * 4;

    const float4* xin = (const float4*)(x + bs0 * 1024);
    #pragma unroll
    for (int it = 0; it < 4; ++it)
        ((float4*)xrow)[it * 256 + tid] = xin[it * 256 + tid];
    __syncthreads();

    {
        const int c = tid & 31, p = tid >> 5;
        float acc[4] = {0.f, 0.f, 0.f, 0.f};
        #pragma unroll 4
        for (int dd = 0; dd < 128; ++dd) {
            const int d = p * 128 + dd;
            const float wv = Wc[d * 32 + c];
            #pragma unroll
            for (int r = 0; r < 4; ++r)
                acc[r] = __builtin_fmaf(xrow[r * 1024 + d], wv, acc[r]);
        }
        #pragma unroll
        for (int r = 0; r < 4; ++r)
            part[r * 256 + p * 32 + c] = acc[r];
    }
    __syncthreads();
    if (tid < 128) {
        const int r = tid >> 5, c = tid & 31;
        float s = bc[c];
        #pragma unroll
        for (int p = 0; p < 8; ++p) s += part[r * 256 + p * 32 + c];
        xc[r * 32 + c] = s;
    }
    __syncthreads();
    {
        const int h = tid & 63;
        const int rr = tid >> 6;           // 0..3
        float ua = b1[h], va = 0.0f;
        #pragma unroll
        for (int cc = 0; cc < 32; ++cc) {
            const float xv = xc[rr * 32 + cc];
            ua = __builtin_fmaf(xv, W1[cc * 64 + h], ua);
            va = __builtin_fmaf(xv, W1[(32 + cc) * 64 + h], va);
        }
        u[(bs0 + rr) * 64 + h] = (f16)ua;
        v[(bs0 + rr) * 64 + h] = (f16)va;
    }
}

// ---------------- Kernel 2: out[b,h,i,j] = sum_k gelu(u[i,k]+v[j,k]) * W2[k,h] + b2[h] --
// D = G_i (16j x 64k) @ W2 (64k x 16h) via 2x mfma_f32_16x16x32_f16 (operands swapped):
// D col = lane&15 = h, row = lg*4+r = j-in-tile -> one dwordx4 store per il.
// Block: 256 thr = 4 waves; tile = 32 i x 64 j. Grid (16,32,2).
__global__ __launch_bounds__(256, 2) void prg_main(
    const f16* __restrict__ u, const f16* __restrict__ v,
    const float* __restrict__ W2, const float* __restrict__ b2,
    float* __restrict__ out)
{
    const int tid  = threadIdx.x;
    const int lane = tid & 63;
    const int w    = tid >> 6;
    const int jb   = blockIdx.x * 64;
    const int ib   = blockIdx.y * 32;
    const int b    = blockIdx.z;

    __shared__ f16 u_lds[32][64];   // 4 KB

    {
        const int row = tid >> 3;
        const int col = (tid & 7) * 8;
        *(uint4*)&u_lds[row][col] =
            *(const uint4*)(u + ((size_t)(b * SDIM + ib + row) * 64 + col));
    }

    const int lg = lane >> 4;   // k-group 0..3
    const int lr = lane & 15;   // A row (j) / B+D col (h)
    const int k0 = lg * 8;

    // A operand rows: j = jb + w*16 + lr ; v kept in registers
    const int jA = jb + w * 16 + lr;
    const f16* vp = v + ((size_t)(b * SDIM + jA) * 64);
    const uint4 vlo = *(const uint4*)(vp + k0);        // k0..k0+7
    const uint4 vhi = *(const uint4*)(vp + k0 + 32);   // k0+32..k0+39

    // B operand = W2 (f16): col h = lr, element e at k = k0+e
    FragH w2lo, w2hi;
    #pragma unroll
    for (int e = 0; e < 4; ++e) {
        H2U a, c;
        a.h = __floats2half2_rn(W2[(k0 + 2*e) * 16 + lr],      W2[(k0 + 2*e + 1) * 16 + lr]);
        c.h = __floats2half2_rn(W2[(k0 + 32 + 2*e) * 16 + lr], W2[(k0 + 32 + 2*e + 1) * 16 + lr]);
        w2lo.u[e] = a.u;
        w2hi.u[e] = c.u;
    }

    const float b2h = b2[lr];   // D col = h = lr, same bias for all 4 acc rows

    __syncthreads();

    // store: lane writes out[b, h=lr, i=ib+il, j = jb + w*16 + lg*4 + {0..3}] -> float4
    float* ob = out + ((size_t)(b * 16 + lr) * SDIM + ib) * SDIM + (jb + w * 16 + lg * 4);

    #pragma unroll 2
    for (int il = 0; il < 32; ++il) {
        const uint4 alo = *(const uint4*)&u_lds[il][k0];
        const uint4 ahi = *(const uint4*)&u_lds[il][k0 + 32];

        FragH glo, ghi;
        glo.u[0] = addgelu_pair(alo.x, vlo.x);
        glo.u[1] = addgelu_pair(alo.y, vlo.y);
        glo.u[2] = addgelu_pair(alo.z, vlo.z);
        glo.u[3] = addgelu_pair(alo.w, vlo.w);
        ghi.u[0] = addgelu_pair(ahi.x, vhi.x);
        ghi.u[1] = addgelu_pair(ahi.y, vhi.y);
        ghi.u[2] = addgelu_pair(ahi.z, vhi.z);
        ghi.u[3] = addgelu_pair(ahi.w, vhi.w);

        f32x4 acc = {b2h, b2h, b2h, b2h};
        acc = __builtin_amdgcn_mfma_f32_16x16x32_f16(glo.f, w2lo.f, acc, 0, 0, 0);
        acc = __builtin_amdgcn_mfma_f32_16x16x32_f16(ghi.f, w2hi.f, acc, 0, 0, 0);

        *(float4*)(ob + (size_t)il * SDIM) = *(float4*)&acc;
    }
}

extern "C" void kernel_launch(void* const* d_in, const int* in_sizes, int n_in,
                              void* d_out, int out_size, void* d_ws, size_t ws_size,
                              hipStream_t stream) {
    const float* x  = (const float*)d_in[0];
    const float* Wc = (const float*)d_in[1];
    const float* bc = (const float*)d_in[2];
    const float* W1 = (const float*)d_in[3];
    const float* b1 = (const float*)d_in[4];
    const float* W2 = (const float*)d_in[5];
    const float* b2 = (const float*)d_in[6];
    float* out = (float*)d_out;

    f16* u = (f16*)d_ws;                 // [B*S*64] f16 = 256 KB
    f16* v = u + 2 * SDIM * 64;          // [B*S*64] f16 = 256 KB

    compute_uv<<<dim3(512), dim3(256), 0, stream>>>(x, Wc, bc, W1, b1, u, v);
    prg_main<<<dim3(16, 32, 2), dim3(256), 0, stream>>>(u, v, W2, b2, out);
}